// Round 7
// baseline (644.455 us; speedup 1.0000x reference)
//
#include <hip/hip_runtime.h>
#include <hip/hip_bf16.h>

#define D_MODEL 1024
#define N_HEADS 16
#define HEAD_DIM 64
#define D_FF 4096
#define SEQ 2048
#define BATCH 4
#define NTOK (BATCH*SEQ)
#define QS 3072   // fused qkv row stride

typedef __attribute__((ext_vector_type(4))) float  f32x4;
typedef __attribute__((ext_vector_type(8))) short  s16x8;
typedef __attribute__((ext_vector_type(4))) unsigned short u16x4;

typedef __attribute__((address_space(1))) const unsigned int gas_u32;
typedef __attribute__((address_space(3))) unsigned int las_u32;

__device__ __forceinline__ void gload_lds16(const void* g, void* l) {
  __builtin_amdgcn_global_load_lds((gas_u32*)g, (las_u32*)l, 16, 0, 0);
}

__device__ __forceinline__ float bf2f(unsigned short u) {
  union { unsigned int i; float f; } v; v.i = ((unsigned int)u) << 16; return v.f;
}
__device__ __forceinline__ unsigned short f2bf(float f) {
  union { float f; unsigned int i; } v; v.f = f;
  return (unsigned short)((v.i + 0x7fffu + ((v.i >> 16) & 1u)) >> 16);
}

// ---------------- fused fp32 -> bf16 weight convert ----------------
__global__ __launch_bounds__(256) void cvt_all_k(const float* __restrict__ qw, const float* __restrict__ kw,
                                                 const float* __restrict__ vw, const float* __restrict__ ow,
                                                 const float* __restrict__ w1, const float* __restrict__ w2,
                                                 const float* __restrict__ w3,
                                                 unsigned short* __restrict__ wqkv, unsigned short* __restrict__ wo,
                                                 unsigned short* __restrict__ b1, unsigned short* __restrict__ b2,
                                                 unsigned short* __restrict__ b3) {
  const long MM = 1 << 20;
  long e = ((long)blockIdx.x*256 + threadIdx.x)*4;   // 16M elements exact, 16384 blocks
  const float* src; unsigned short* dst; long off;
  if      (e <    MM) { src = qw; dst = wqkv;        off = e; }
  else if (e <  2*MM) { src = kw; dst = wqkv + MM;   off = e - MM; }
  else if (e <  3*MM) { src = vw; dst = wqkv + 2*MM; off = e - 2*MM; }
  else if (e <  4*MM) { src = ow; dst = wo;          off = e - 3*MM; }
  else if (e <  8*MM) { src = w1; dst = b1;          off = e - 4*MM; }
  else if (e < 12*MM) { src = w2; dst = b2;          off = e - 8*MM; }
  else                { src = w3; dst = b3;          off = e - 12*MM; }
  f32x4 v = *(const f32x4*)&src[off];
  u16x4 o;
  #pragma unroll
  for (int c=0;c<4;c++) o[c] = f2bf(v[c]);
  *(u16x4*)&dst[off] = o;
}

// ---------------- RoPE cos/sin tables: [SEQ][32] ----------------
__global__ __launch_bounds__(256) void rope_tables_k(const int* __restrict__ pos,
                                                     float* __restrict__ cosT,
                                                     float* __restrict__ sinT) {
  int idx = blockIdx.x*256 + threadIdx.x;      // SEQ*32 exact
  int t = idx >> 5, i = idx & 31;
  float p  = (float)pos[t];
  float fr = powf(10000.0f, -(float)i * (1.0f/32.0f));
  float ang = p * fr;
  cosT[idx] = cosf(ang);
  sinT[idx] = sinf(ang);
}

// ---------------- RMSNorm: fp32 in -> bf16 out ----------------
__global__ __launch_bounds__(256) void rmsnorm_k(const float* __restrict__ x,
                                                 const float* __restrict__ wgt,
                                                 unsigned short* __restrict__ out) {
  const long row = blockIdx.x;
  const int t = threadIdx.x;
  f32x4 v = *(const f32x4*)&x[row*D_MODEL + t*4];
  float ss = v[0]*v[0] + v[1]*v[1] + v[2]*v[2] + v[3]*v[3];
  #pragma unroll
  for (int off=1; off<64; off<<=1) ss += __shfl_xor(ss, off, 64);
  __shared__ float red[4];
  if ((t & 63) == 0) red[t >> 6] = ss;
  __syncthreads();
  float tot = red[0] + red[1] + red[2] + red[3];
  float inv = rsqrtf(tot * (1.0f/D_MODEL) + 1e-5f);
  f32x4 wv = *(const f32x4*)&wgt[t*4];
  u16x4 o;
  #pragma unroll
  for (int c=0;c<4;c++) o[c] = f2bf(v[c] * inv * wv[c]);
  *(u16x4*)&out[row*D_MODEL + t*4] = o;
}

// ---------------- RoPE in-place on fused qkv; Q pre-scaled by 1/8 ----------------
__global__ __launch_bounds__(256) void rope_k(unsigned short* __restrict__ qkv,
                                              const float* __restrict__ cosT,
                                              const float* __restrict__ sinT) {
  long idx = (long)blockIdx.x*256 + threadIdx.x;   // NTOK*16*8 exact
  int ig = (int)(idx & 7);
  long th = idx >> 3;
  int h = (int)(th & 15);
  long bt = th >> 4;
  int t = (int)(bt & (SEQ-1));
  long off = bt*QS + h*HEAD_DIM + ig*8;
  f32x4 cs = *(const f32x4*)&cosT[t*32 + ig*4];
  f32x4 sn = *(const f32x4*)&sinT[t*32 + ig*4];
  s16x8 qv = *(const s16x8*)&qkv[off];
  s16x8 kv = *(const s16x8*)&qkv[off + 1024];
  s16x8 qo, ko;
  #pragma unroll
  for (int p=0;p<4;p++) {
    float q1 = bf2f((unsigned short)qv[2*p]), q2 = bf2f((unsigned short)qv[2*p+1]);
    qo[2*p]   = (short)f2bf((q1*cs[p] - q2*sn[p]) * 0.125f);  // fold 1/sqrt(64)
    qo[2*p+1] = (short)f2bf((q1*sn[p] + q2*cs[p]) * 0.125f);
    float k1 = bf2f((unsigned short)kv[2*p]), k2 = bf2f((unsigned short)kv[2*p+1]);
    ko[2*p]   = (short)f2bf(k1*cs[p] - k2*sn[p]);
    ko[2*p+1] = (short)f2bf(k1*sn[p] + k2*cs[p]);
  }
  *(s16x8*)&qkv[off] = qo;
  *(s16x8*)&qkv[off + 1024] = ko;
}

// ---------------- GEMM: m201-style 8-phase (4 phases/K-tile), counted vmcnt ----------------
// Generic over (BM, BN, WR, WC); BK=64, 512 threads (8 waves), double-buffered LDS.
// Phase plan for tile t (bufs ba=t&1):
//   P1: read A-mh0 + B-nh0 of tile t; stage Bh1(t+1) -> buf ba^1; bar; MFMA(mh0,nh0); bar
//   P2: read A-mh1 + B-nh1;           stage Ah0(t+2) -> buf ba;   bar; MFMA(mh1,nh0); bar
//   P3:                               stage Ah1(t+2) -> buf ba;   bar; MFMA(mh0,nh1); bar
//   P4:                               stage Bh0(t+2) -> buf ba;   bar; MFMA(mh1,nh1);
//       vmcnt(2*LA+LB) [keeps t+2's 3 staged halves in flight, retires all of t+1]; bar
// Region safety: each LDS half overwritten >=1 barrier after its last read
// (A-h0 read P1 / staged P2; A-h1 read P2 / staged P3; B-h0 read P1 / staged P4;
//  B-h1 read P2 / staged next-block P1). vmcnt(0) only in the last two tiles.
template<int EPI, int BM, int BN, int WR, int WC>
__global__ __launch_bounds__(512, 2) void gemm8p(const unsigned short* __restrict__ A,
                                                 const unsigned short* __restrict__ W,
                                                 unsigned short* __restrict__ Cb,
                                                 float* __restrict__ Cf,
                                                 const float* __restrict__ resid,
                                                 int M, int N, int K) {
  constexpr int WTM = BM / WR;
  constexpr int WTN = BN / WC;
  constexpr int MR  = WTM / 16;
  constexpr int NR  = WTN / 16;
  constexpr int M2  = MR / 2, N2 = NR / 2;
  constexpr int LA  = BM / 128;          // gloads/thread per A-half
  constexpr int LB  = BN / 128;          // gloads/thread per B-half
  constexpr int VMC = 2*LA + LB;         // boundary vmcnt

  __shared__ __align__(16) unsigned short As[2][BM*64];
  __shared__ __align__(16) unsigned short Bs[2][BN*64];

  const int nwg = gridDim.x * gridDim.y;
  int orig = blockIdx.y * gridDim.x + blockIdx.x;
  int swz = orig;
  if ((nwg & 7) == 0) { int cpx = nwg >> 3; swz = (orig & 7) * cpx + (orig >> 3); }
  const int bx = swz % gridDim.x;
  const int by = swz / gridDim.x;

  const int tid = threadIdx.x;
  const int wid = tid >> 6;
  const int l  = tid & 63;
  const int lr = l & 15;
  const int lg = l >> 4;
  const int wr = wid / WC;
  const int wc = wid % WC;

  const long rowA0 = (long)by * BM;
  const long rowB0 = (long)bx * BN;
  const int nk = K >> 6;

  auto stA = [&](int b, int kt, int h) {   // stage A half h (BM/2 rows)
    #pragma unroll
    for (int it = 0; it < LA; ++it) {
      int c = it*512 + tid;
      int row = h*(BM/2) + (c >> 3);
      int csw = (c & 7) ^ (row & 7);
      gload_lds16(&A[(rowA0 + row)*(long)K + kt + csw*8], &As[b][row*64 + (c&7)*8]);
    }
  };
  auto stB = [&](int b, int kt, int h) {   // stage B half h (BN/2 rows)
    #pragma unroll
    for (int it = 0; it < LB; ++it) {
      int c = it*512 + tid;
      int row = h*(BN/2) + (c >> 3);
      int csw = (c & 7) ^ (row & 7);
      gload_lds16(&W[(rowB0 + row)*(long)K + kt + csw*8], &Bs[b][row*64 + (c&7)*8]);
    }
  };

  f32x4 acc[MR][NR] = {};
  s16x8 afr[MR][2], bfr[NR][2];

  auto ldA = [&](int b, int mh) {
    #pragma unroll
    for (int m=0;m<M2;m++) {
      int row = wr*WTM + (mh*M2+m)*16 + lr;
      #pragma unroll
      for (int kk=0;kk<2;kk++)
        afr[mh*M2+m][kk] = *(const s16x8*)&As[b][row*64 + ((kk*4+lg)^(row&7))*8];
    }
  };
  auto ldB = [&](int b, int nh) {
    #pragma unroll
    for (int n=0;n<N2;n++) {
      int row = wc*WTN + (nh*N2+n)*16 + lr;
      #pragma unroll
      for (int kk=0;kk<2;kk++)
        bfr[nh*N2+n][kk] = *(const s16x8*)&Bs[b][row*64 + ((kk*4+lg)^(row&7))*8];
    }
  };
  auto mm = [&](int mh, int nh) {
    #pragma unroll
    for (int kk=0;kk<2;kk++)
      #pragma unroll
      for (int m=0;m<M2;m++)
        #pragma unroll
        for (int n=0;n<N2;n++)
          acc[mh*M2+m][nh*N2+n] = __builtin_amdgcn_mfma_f32_16x16x32_bf16(
              afr[mh*M2+m][kk], bfr[nh*N2+n][kk], acc[mh*M2+m][nh*N2+n], 0,0,0);
  };

  // prologue: tile0 fully + 3 halves of tile1  (nk >= 16 always here)
  stA(0,0,0); stA(0,0,1); stB(0,0,0); stB(0,0,1);
  stA(1,64,0); stA(1,64,1); stB(1,64,0);
  asm volatile("s_waitcnt vmcnt(%0)" :: "n"(VMC) : "memory");
  __builtin_amdgcn_s_barrier();

  int ba = 0;
  for (int t = 0; t < nk; ++t) {
    const int kt1 = (t+1) << 6, kt2 = (t+2) << 6;
    const bool s2 = (t+2) < nk;
    // P1
    ldA(ba, 0); ldB(ba, 0);
    if (t+1 < nk) stB(ba^1, kt1, 1);
    __builtin_amdgcn_s_barrier();
    __builtin_amdgcn_s_setprio(1); mm(0,0); __builtin_amdgcn_s_setprio(0);
    __builtin_amdgcn_s_barrier();
    // P2
    ldA(ba, 1); ldB(ba, 1);
    if (s2) stA(ba, kt2, 0);
    __builtin_amdgcn_s_barrier();
    __builtin_amdgcn_s_setprio(1); mm(1,0); __builtin_amdgcn_s_setprio(0);
    __builtin_amdgcn_s_barrier();
    // P3
    if (s2) stA(ba, kt2, 1);
    __builtin_amdgcn_s_barrier();
    __builtin_amdgcn_s_setprio(1); mm(0,1); __builtin_amdgcn_s_setprio(0);
    __builtin_amdgcn_s_barrier();
    // P4
    if (s2) stB(ba, kt2, 0);
    __builtin_amdgcn_s_barrier();
    __builtin_amdgcn_s_setprio(1); mm(1,1); __builtin_amdgcn_s_setprio(0);
    if (s2)             { asm volatile("s_waitcnt vmcnt(%0)" :: "n"(VMC) : "memory"); }
    else if (t+1 < nk)  { asm volatile("s_waitcnt vmcnt(0)" ::: "memory"); }
    __builtin_amdgcn_s_barrier();
    ba ^= 1;
  }

  #pragma unroll
  for (int mi=0;mi<MR;mi++)
    #pragma unroll
    for (int n=0;n<NR;n++)
      #pragma unroll
      for (int rr=0;rr<4;rr++) {
        long row = rowA0 + wr*WTM + mi*16 + lg*4 + rr;
        long col = rowB0 + wc*WTN + n*16 + lr;
        float val = acc[mi][n][rr];
        if constexpr (EPI == 0) {
          Cb[row*(long)N + col] = f2bf(val);
        } else {
          Cf[row*(long)N + col] = resid[row*(long)N + col] + val;
        }
      }
}

// ---------------- Flash attention (causal), unchanged ----------------
__global__ __launch_bounds__(256) void attn_k(const unsigned short* __restrict__ QKV,
                                              unsigned short* __restrict__ O) {
  const int bh = blockIdx.x;
  const int b = bh >> 4;
  const int h = bh & 15;
  const int tid = threadIdx.x;
  const int w  = tid >> 6;
  const int l  = tid & 63;
  const int lr = l & 15;
  const int lg = l >> 4;

  const unsigned short* Qp = QKV;
  const unsigned short* Kp = QKV + 1024;
  const unsigned short* Vp = QKV + 2048;

  __shared__ __align__(16) unsigned short Ks[2][64*64];
  __shared__ __align__(16) unsigned short Vs[2][64*64];
  __shared__ __align__(16) unsigned short Ps[4][16][64];

  const int skv = tid >> 2;
  const int sd0 = (tid & 3) * 16;
  const long hbase = (long)(b*SEQ)*QS + h*HEAD_DIM;

  for (int pass = 0; pass < 2; ++pass) {
    const int qt = pass ? 31 - (int)blockIdx.y : (int)blockIdx.y;
    const int q0 = qt * 64;
    const int ntile = qt + 1;

    const long rowQ = (long)(b*SEQ + q0 + w*16 + lr);
    s16x8 qf0 = *(const s16x8*)&Qp[rowQ*QS + h*HEAD_DIM + lg*8];
    s16x8 qf1 = *(const s16x8*)&Qp[rowQ*QS + h*HEAD_DIM + 32 + lg*8];

    float mi = -1e30f, li = 0.f;
    f32x4 oa[4] = {};

    #pragma unroll
    for (int it=0; it<2; ++it) {
      int chunk = it*256 + tid;
      int row = chunk >> 3;
      int csw = (chunk & 7) ^ (row & 7);
      gload_lds16(&Kp[hbase + (long)row*QS + csw*8], &Ks[0][chunk*8]);
    }
    {
      const unsigned short* src = &Vp[hbase + (long)skv*QS + sd0];
      s16x8 v0 = *(const s16x8*)&src[0];
      s16x8 v1 = *(const s16x8*)&src[8];
      #pragma unroll
      for (int i=0;i<16;i++) {
        int d = sd0 + i;
        int key = (d&7) ^ ((d>>3)&7);
        int c = (skv>>3) ^ key;
        Vs[0][d*64 + c*8 + (skv&7)] = (unsigned short)(i<8 ? v0[i] : v1[i-8]);
      }
    }
    __syncthreads();

    for (int t=0; t<ntile; ++t) {
      const int kv0 = t*64;
      const int cur = t & 1;
      const int nb  = cur ^ 1;
      const bool more = (t+1 < ntile);

      s16x8 v0, v1;
      if (more) {
        #pragma unroll
        for (int it=0; it<2; ++it) {
          int chunk = it*256 + tid;
          int row = chunk >> 3;
          int csw = (chunk & 7) ^ (row & 7);
          gload_lds16(&Kp[hbase + (long)(kv0 + 64 + row)*QS + csw*8], &Ks[nb][chunk*8]);
        }
        const unsigned short* src = &Vp[hbase + (long)(kv0 + 64 + skv)*QS + sd0];
        v0 = *(const s16x8*)&src[0];
        v1 = *(const s16x8*)&src[8];
      }

      f32x4 s[4];
      __builtin_amdgcn_s_setprio(1);
      #pragma unroll
      for (int j=0;j<4;j++) {
        int krow = j*16 + lr;
        s16x8 kf0 = *(const s16x8*)&Ks[cur][krow*64 + ((lg)     ^ (krow&7))*8];
        s16x8 kf1 = *(const s16x8*)&Ks[cur][krow*64 + ((4 + lg) ^ (krow&7))*8];
        f32x4 acc = {};
        acc = __builtin_amdgcn_mfma_f32_16x16x32_bf16(kf0, qf0, acc, 0,0,0);
        acc = __builtin_amdgcn_mfma_f32_16x16x32_bf16(kf1, qf1, acc, 0,0,0);
        s[j] = acc;
      }
      __builtin_amdgcn_s_setprio(0);

      if (t == ntile-1) {
        #pragma unroll
        for (int j=0;j<4;j++)
          #pragma unroll
          for (int r=0;r<4;r++)
            if (kv0 + j*16 + lg*4 + r > q0 + w*16 + lr) s[j][r] = -1e30f;
      }

      float pmax = s[0][0];
      #pragma unroll
      for (int j=0;j<4;j++)
        #pragma unroll
        for (int r=0;r<4;r++) pmax = fmaxf(pmax, s[j][r]);
      pmax = fmaxf(pmax, __shfl_xor(pmax, 16, 64));
      pmax = fmaxf(pmax, __shfl_xor(pmax, 32, 64));
      float mn = fmaxf(mi, pmax);
      float al = __expf(mi - mn);
      mi = mn;
      float psum = 0.f;
      #pragma unroll
      for (int j=0;j<4;j++)
        #pragma unroll
        for (int r=0;r<4;r++) {
          float p = __expf(s[j][r] - mn);
          s[j][r] = p;
          psum += p;
        }
      psum += __shfl_xor(psum, 16, 64);
      psum += __shfl_xor(psum, 32, 64);
      li = li*al + psum;

      float alq[4];
      #pragma unroll
      for (int r=0;r<4;r++) alq[r] = __shfl(al, lg*4 + r, 64);
      #pragma unroll
      for (int d=0;d<4;d++)
        #pragma unroll
        for (int r=0;r<4;r++) oa[d][r] *= alq[r];

      #pragma unroll
      for (int j=0;j<4;j++)
        #pragma unroll
        for (int r=0;r<4;r++) {
          int k = j*16 + lg*4 + r;
          int pos = ((k>>3) ^ (lr&7))*8 + (k&7);
          Ps[w][lr][pos] = f2bf(s[j][r]);
        }

      if (more) {
        #pragma unroll
        for (int i=0;i<16;i++) {
          int d = sd0 + i;
          int key = (d&7) ^ ((d>>3)&7);
          int c = (skv>>3) ^ key;
          Vs[nb][d*64 + c*8 + (skv&7)] = (unsigned short)(i<8 ? v0[i] : v1[i-8]);
        }
      }

      __builtin_amdgcn_s_setprio(1);
      #pragma unroll
      for (int kk=0;kk<2;kk++) {
        s16x8 pa = *(const s16x8*)&Ps[w][lr][((kk*4 + lg) ^ (lr&7))*8];
        #pragma unroll
        for (int d=0;d<4;d++) {
          int vrow = d*16 + lr;
          int key = (vrow&7) ^ ((vrow>>3)&7);
          int c = (kk*4 + lg) ^ key;
          s16x8 vb = *(const s16x8*)&Vs[cur][vrow*64 + c*8];
          oa[d] = __builtin_amdgcn_mfma_f32_16x16x32_bf16(pa, vb, oa[d], 0,0,0);
        }
      }
      __builtin_amdgcn_s_setprio(0);
      __syncthreads();
    }

    float liq[4];
    #pragma unroll
    for (int r=0;r<4;r++) liq[r] = __shfl(li, lg*4 + r, 64);
    #pragma unroll
    for (int d=0;d<4;d++)
      #pragma unroll
      for (int r=0;r<4;r++) {
        long row = (long)(b*SEQ + q0 + w*16 + lg*4 + r);
        O[row*D_MODEL + h*HEAD_DIM + d*16 + lr] = f2bf(oa[d][r] / liq[r]);
      }
  }
}

// ---------------- SwiGLU ----------------
__global__ __launch_bounds__(256) void swiglu_k(unsigned short* __restrict__ a,
                                                const unsigned short* __restrict__ g) {
  long i = ((long)blockIdx.x*256 + threadIdx.x)*8;
  s16x8 av = *(const s16x8*)&a[i];
  s16x8 gv = *(const s16x8*)&g[i];
  s16x8 o;
  #pragma unroll
  for (int c=0;c<8;c++) {
    float xx = bf2f((unsigned short)av[c]);
    float yy = bf2f((unsigned short)gv[c]);
    float sg = 1.0f / (1.0f + __expf(-xx));
    o[c] = (short)f2bf(xx * sg * yy);
  }
  *(s16x8*)&a[i] = o;
}

extern "C" void kernel_launch(void* const* d_in, const int* in_sizes, int n_in,
                              void* d_out, int out_size, void* d_ws, size_t ws_size,
                              hipStream_t stream) {
  (void)in_sizes; (void)n_in; (void)out_size; (void)ws_size;
  const float* x    = (const float*)d_in[0];
  const int*   tpos = (const int*)d_in[1];
  const float* ln1  = (const float*)d_in[2];
  const float* qw   = (const float*)d_in[3];
  const float* kw   = (const float*)d_in[4];
  const float* vw   = (const float*)d_in[5];
  const float* ow   = (const float*)d_in[6];
  const float* ln2  = (const float*)d_in[7];
  const float* w1   = (const float*)d_in[8];
  const float* w2   = (const float*)d_in[9];
  const float* w3   = (const float*)d_in[10];
  float* out = (float*)d_out;

  char* ws = (char*)d_ws;
  size_t off = 0;
  auto nalloc = [&](size_t b) { void* p = ws + off; off += (b + 255) & ~(size_t)255; return p; };

  unsigned short* wqkvb = (unsigned short*)nalloc((size_t)3072*D_MODEL*2);
  unsigned short* wob   = (unsigned short*)nalloc((size_t)D_MODEL*D_MODEL*2);
  unsigned short* w1b   = (unsigned short*)nalloc((size_t)D_FF*D_MODEL*2);
  unsigned short* w3b   = (unsigned short*)nalloc((size_t)D_FF*D_MODEL*2);
  unsigned short* w2b   = (unsigned short*)nalloc((size_t)D_MODEL*D_FF*2);
  float* cosT = (float*)nalloc((size_t)SEQ*32*4);
  float* sinT = (float*)nalloc((size_t)SEQ*32*4);
  unsigned short* hbuf = (unsigned short*)nalloc((size_t)NTOK*D_MODEL*2);
  unsigned short* qkv  = (unsigned short*)nalloc((size_t)NTOK*QS*2);      // 48MB
  unsigned short* ctxb = (unsigned short*)nalloc((size_t)NTOK*D_MODEL*2); // 16MB, adjacent
  float* x2 = (float*)nalloc((size_t)NTOK*D_MODEL*4);
  unsigned short* gbuf = (unsigned short*)nalloc((size_t)NTOK*D_FF*2);
  unsigned short* abuf = qkv;   // qkv..ctxb span = exactly NTOK*D_FF bf16, free after O-proj

  cvt_all_k<<<16384,256,0,stream>>>(qw, kw, vw, ow, w1, w2, w3,
                                    wqkvb, wob, w1b, w2b, w3b);
  rope_tables_k<<<SEQ*32/256,256,0,stream>>>(tpos, cosT, sinT);

  rmsnorm_k<<<NTOK,256,0,stream>>>(x, ln1, hbuf);
  gemm8p<0,256,256,2,4><<<dim3(12,32),512,0,stream>>>(hbuf, wqkvb, qkv, nullptr, nullptr, NTOK, QS, D_MODEL);
  rope_k<<<4096,256,0,stream>>>(qkv, cosT, sinT);
  attn_k<<<dim3(64,16),256,0,stream>>>(qkv, ctxb);
  gemm8p<1,256,128,4,2><<<dim3(8,32),512,0,stream>>>(ctxb, wob, nullptr, x2, x, NTOK, D_MODEL, D_MODEL);

  rmsnorm_k<<<NTOK,256,0,stream>>>(x2, ln2, hbuf);
  gemm8p<0,256,256,2,4><<<dim3(16,32),512,0,stream>>>(hbuf, w1b, abuf, nullptr, nullptr, NTOK, D_FF, D_MODEL);
  gemm8p<0,256,256,2,4><<<dim3(16,32),512,0,stream>>>(hbuf, w3b, gbuf, nullptr, nullptr, NTOK, D_FF, D_MODEL);
  swiglu_k<<<(long)NTOK*D_FF/8/256,256,0,stream>>>(abuf, gbuf);
  gemm8p<1,256,128,4,2><<<dim3(8,32),512,0,stream>>>(abuf, w2b, nullptr, out, x2, NTOK, D_MODEL, D_FF);
}